// Round 1
// baseline (550.845 us; speedup 1.0000x reference)
//
#include <hip/hip_runtime.h>
#include <hip/hip_bf16.h>

// MatchingLayer: B=8, S=2048, H=1024
//   scores = (X X^T)/32 -> mask -> softmax -> context = P X
//   matching = [X|context] @ W + b -> LayerNorm
// Strategy: bf16 MFMA for all 3 GEMMs (threshold 0.108 permits), softmax via
// exp-then-normalize (no max-subtract needed: max logit ~35, fp32-safe).
// WORKSPACE REQUIREMENT: 172,032,000 bytes.

typedef unsigned short ushort_t;
typedef __attribute__((ext_vector_type(8))) short short8;
typedef __attribute__((ext_vector_type(4))) float float4v;

__device__ inline float b2f(unsigned int u) {
    union { unsigned int i; float f; } v; v.i = u << 16; return v.f;
}
__device__ inline ushort_t f2b(float f) {
    __hip_bfloat16 h = __float2bfloat16(f);
    return __builtin_bit_cast(ushort_t, h);
}

#define BM 128
#define BN 128
#define BK 64
#define LDSS 72   // bf16 elems; 144B row stride = 9x16B (aligned), 2-way bank conflict only (free)

// C[m][n] = sum_k A[m][k] * B[n][k]   (A: [M][K] row-major via lda; B: [N][K] row-major via ldb)
// A is dual-sourced: k0 >= kSplit reads A2 at k0-kSplit (for the [X|context] concat).
// EPI 1: v = exp(v*scale*mask - 1e9*(1-mask)) -> bf16 outb    (QK^T -> E)
// EPI 2: v = v / rowsum[row] -> bf16 outb                     (E@X^T -> context)
// EPI 3: v = v + bias[col] -> fp32 outf                       (cat@W -> matching)
template<int EPI>
__global__ __launch_bounds__(256, 2)
void gemm_bt(const ushort_t* __restrict__ A, const ushort_t* __restrict__ A2, int kSplit,
             const ushort_t* __restrict__ B,
             int M, int N, int K, int lda, int ldb, int ldc,
             long aBS, long bBS, long cBS,
             const float* __restrict__ mask, long mBS, float scale,
             const float* __restrict__ rowsum,
             const float* __restrict__ bias,
             ushort_t* __restrict__ outb, float* __restrict__ outf)
{
    __shared__ ushort_t As[BM * LDSS];
    __shared__ ushort_t Bs[BN * LDSS];

    const int tid = threadIdx.x;
    const int z = blockIdx.z;
    A  += (size_t)z * aBS;
    A2 += (size_t)z * aBS;
    B  += (size_t)z * bBS;
    if (EPI == 1) mask += (size_t)z * mBS;
    if (EPI == 2) rowsum += (size_t)z * M;
    if (EPI != 3) outb += (size_t)z * cBS;

    const int bm = blockIdx.y * BM;
    const int bn = blockIdx.x * BN;
    const int wave = tid >> 6, lane = tid & 63;
    const int wm = (wave >> 1) * 64, wn = (wave & 1) * 64;
    const int q = lane >> 4, l15 = lane & 15;
    const int sr = tid >> 3;          // staging row 0..31
    const int sc = (tid & 7) * 8;     // staging col chunk

    float4v acc[4][4];
#pragma unroll
    for (int i = 0; i < 4; i++)
#pragma unroll
        for (int j = 0; j < 4; j++) acc[i][j] = (float4v){0.f, 0.f, 0.f, 0.f};

    for (int k0 = 0; k0 < K; k0 += BK) {
        const ushort_t* aSrc = A;
        int ka = k0;
        if (k0 >= kSplit) { aSrc = A2; ka = k0 - kSplit; }
#pragma unroll
        for (int i = 0; i < 4; i++) {
            const int row = sr + i * 32;
            uint4 av = *(const uint4*)(aSrc + (size_t)(bm + row) * lda + ka + sc);
            uint4 bv = *(const uint4*)(B    + (size_t)(bn + row) * ldb + k0 + sc);
            *(uint4*)(&As[row * LDSS + sc]) = av;
            *(uint4*)(&Bs[row * LDSS + sc]) = bv;
        }
        __syncthreads();
#pragma unroll
        for (int kk = 0; kk < BK; kk += 32) {
            short8 af[4], bfv[4];
#pragma unroll
            for (int mi = 0; mi < 4; mi++)
                af[mi] = *(const short8*)(&As[(wm + mi * 16 + l15) * LDSS + kk + q * 8]);
#pragma unroll
            for (int ni = 0; ni < 4; ni++)
                bfv[ni] = *(const short8*)(&Bs[(wn + ni * 16 + l15) * LDSS + kk + q * 8]);
#pragma unroll
            for (int mi = 0; mi < 4; mi++)
#pragma unroll
                for (int ni = 0; ni < 4; ni++)
                    acc[mi][ni] = __builtin_amdgcn_mfma_f32_16x16x32_bf16(
                        af[mi], bfv[ni], acc[mi][ni], 0, 0, 0);
        }
        __syncthreads();
    }

    // Epilogue.  D layout (verified m89): col = lane&15, row = (lane>>4)*4 + reg
#pragma unroll
    for (int mi = 0; mi < 4; mi++) {
#pragma unroll
        for (int r = 0; r < 4; r++) {
            const int row = bm + wm + mi * 16 + q * 4 + r;
            const size_t ro = (size_t)row * ldc;
            float rsinv = 1.f;
            if (EPI == 2) rsinv = 1.0f / rowsum[row];
#pragma unroll
            for (int ni = 0; ni < 4; ni++) {
                const int col = bn + wn + ni * 16 + l15;
                float v = acc[mi][ni][r];
                if (EPI == 1) {
                    const float m = mask[(size_t)row * N + col];
                    v = __expf(v * scale * m - 1e9f * (1.0f - m));
                    outb[ro + col] = f2b(v);
                } else if (EPI == 2) {
                    outb[ro + col] = f2b(v * rsinv);
                } else {
                    outf[ro + col] = v + bias[col];
                }
            }
        }
    }
}

// fp32 [R][C] (batched, z) -> outT bf16 [C][R]; optionally outS bf16 [R][C].
__global__ __launch_bounds__(256)
void conv_trans(const float* __restrict__ in, ushort_t* __restrict__ outT,
                ushort_t* __restrict__ outS, int R, int C)
{
    __shared__ float tile[64][65];
    const int tx = threadIdx.x & 15, ty = threadIdx.x >> 4;
    const size_t zoff = (size_t)blockIdx.z * R * C;
    const int r0 = blockIdx.y * 64, c0 = blockIdx.x * 64;
#pragma unroll
    for (int j = 0; j < 4; j++) {
        const int r = ty + j * 16;
        const float4 v = *(const float4*)(in + zoff + (size_t)(r0 + r) * C + c0 + tx * 4);
        tile[r][tx * 4 + 0] = v.x;
        tile[r][tx * 4 + 1] = v.y;
        tile[r][tx * 4 + 2] = v.z;
        tile[r][tx * 4 + 3] = v.w;
        if (outS) {
            ushort4 o;
            o.x = f2b(v.x); o.y = f2b(v.y); o.z = f2b(v.z); o.w = f2b(v.w);
            *(ushort4*)(outS + zoff + (size_t)(r0 + r) * C + c0 + tx * 4) = o;
        }
    }
    __syncthreads();
    ushort_t* tp = outT + zoff;
#pragma unroll
    for (int j = 0; j < 4; j++) {
        const int cc = ty + j * 16;
        ushort4 o;
        o.x = f2b(tile[tx * 4 + 0][cc]);
        o.y = f2b(tile[tx * 4 + 1][cc]);
        o.z = f2b(tile[tx * 4 + 2][cc]);
        o.w = f2b(tile[tx * 4 + 3][cc]);
        *(ushort4*)(tp + (size_t)(c0 + cc) * R + r0 + tx * 4) = o;
    }
}

// rowsum[row] = sum over 2048 bf16 of E[row][*]; one wave per row.
__global__ __launch_bounds__(256)
void rowsum_k(const ushort_t* __restrict__ E, float* __restrict__ rowsum)
{
    const long row = (long)blockIdx.x * 4 + (threadIdx.x >> 6);
    const int lane = threadIdx.x & 63;
    const ushort_t* p = E + row * 2048;
    float s = 0.f;
#pragma unroll
    for (int i = 0; i < 4; i++) {
        const uint4 u = *(const uint4*)(p + i * 512 + lane * 8);
        s += b2f(u.x & 0xffffu) + b2f(u.x >> 16) + b2f(u.y & 0xffffu) + b2f(u.y >> 16)
           + b2f(u.z & 0xffffu) + b2f(u.z >> 16) + b2f(u.w & 0xffffu) + b2f(u.w >> 16);
    }
#pragma unroll
    for (int off = 32; off > 0; off >>= 1) s += __shfl_down(s, off);
    if (lane == 0) rowsum[row] = s;
}

// LayerNorm over H=1024, one block (256 thr) per row.
__global__ __launch_bounds__(256)
void ln_k(const float* __restrict__ Mt, const float* __restrict__ gamma,
          const float* __restrict__ beta, float* __restrict__ out)
{
    const size_t row = blockIdx.x;
    const int tid = threadIdx.x;
    const float4 v = *(const float4*)(Mt + row * 1024 + tid * 4);
    float s  = v.x + v.y + v.z + v.w;
    float s2 = v.x * v.x + v.y * v.y + v.z * v.z + v.w * v.w;
#pragma unroll
    for (int off = 32; off > 0; off >>= 1) {
        s  += __shfl_down(s, off);
        s2 += __shfl_down(s2, off);
    }
    __shared__ float red[8];
    const int wave = tid >> 6, lane = tid & 63;
    if (lane == 0) { red[wave] = s; red[4 + wave] = s2; }
    __syncthreads();
    s  = red[0] + red[1] + red[2] + red[3];
    s2 = red[4] + red[5] + red[6] + red[7];
    const float mu  = s * (1.0f / 1024.0f);
    const float var = s2 * (1.0f / 1024.0f) - mu * mu;
    const float rinv = rsqrtf(var + 1e-12f);
    const float4 g = *(const float4*)(gamma + tid * 4);
    const float4 b = *(const float4*)(beta + tid * 4);
    float4 o;
    o.x = (v.x - mu) * rinv * g.x + b.x;
    o.y = (v.y - mu) * rinv * g.y + b.y;
    o.z = (v.z - mu) * rinv * g.z + b.z;
    o.w = (v.w - mu) * rinv * g.w + b.w;
    *(float4*)(out + row * 1024 + tid * 4) = o;
}

extern "C" void kernel_launch(void* const* d_in, const int* in_sizes, int n_in,
                              void* d_out, int out_size, void* d_ws, size_t ws_size,
                              hipStream_t stream)
{
    const float* X     = (const float*)d_in[0];  // [8,2048,1024]
    const float* masks = (const float*)d_in[1];  // [8,2048,2048]
    const float* Wm    = (const float*)d_in[2];  // [2048,1024]
    const float* bias  = (const float*)d_in[3];  // [1024]
    const float* gamma = (const float*)d_in[4];  // [1024]
    const float* beta  = (const float*)d_in[5];  // [1024]
    float* out = (float*)d_out;
    char* ws = (char*)d_ws;

    const int B = 8, S = 2048, H = 1024;

    // workspace layout (bytes): total 172,032,000
    ushort_t* Xb  = (ushort_t*)(ws);              // 33,554,432  X bf16 [B][S][H]
    ushort_t* XT  = (ushort_t*)(ws + 33554432);   // 33,554,432  X^T bf16 [B][H][S]
    ushort_t* WT  = (ushort_t*)(ws + 67108864);   //  4,194,304  W^T bf16 [H][2H]
    ushort_t* E   = (ushort_t*)(ws + 71303168);   // 67,108,864  exp(logits) bf16 [B][S][S]
    float*    rs  = (float*)   (ws + 138412032);  //     65,536  rowsums [B][S]
    ushort_t* CTX = (ushort_t*)(ws + 138477568);  // 33,554,432  context bf16 [B][S][H]
    float* matching = (float*)E;                  // alias: E dead after GEMM2 (64MB exactly)

    conv_trans<<<dim3(16, 32, 8), 256, 0, stream>>>(X, XT, Xb, S, H);
    conv_trans<<<dim3(16, 32, 1), 256, 0, stream>>>(Wm, WT, nullptr, 2 * H, H);

    const float scale = 0.03125f;  // 1/sqrt(1024)

    // GEMM1: E = exp(mask(scale * X X^T))
    gemm_bt<1><<<dim3(16, 16, 8), 256, 0, stream>>>(
        Xb, Xb, 1 << 30, Xb,
        S, S, H, H, H, S,
        (long)S * H, (long)S * H, (long)S * S,
        masks, (long)S * S, scale, nullptr, nullptr, E, nullptr);

    rowsum_k<<<(B * S) / 4, 256, 0, stream>>>(E, rs);

    // GEMM2: CTX = (E . XT^T) / rowsum
    gemm_bt<2><<<dim3(8, 16, 8), 256, 0, stream>>>(
        E, E, 1 << 30, XT,
        S, H, S, S, S, H,
        (long)S * S, (long)H * S, (long)S * H,
        nullptr, 0, 1.0f, rs, nullptr, CTX, nullptr);

    // GEMM3: matching = [Xb|CTX] @ WT^T + bias
    gemm_bt<3><<<dim3(8, 128, 1), 256, 0, stream>>>(
        Xb, CTX, H, WT,
        B * S, H, 2 * H, H, 2 * H, H,
        0, 0, 0,
        nullptr, 0, 1.0f, nullptr, bias, nullptr, matching);

    ln_k<<<B * S, 256, 0, stream>>>(matching, gamma, beta, out);
}